// Round 17
// baseline (782.663 us; speedup 1.0000x reference)
//
#include <hip/hip_runtime.h>
#include <cmath>

static constexpr int Bn = 128;
static constexpr int Nn = 256;
static constexpr int META_PB = 131072;   // per-batch metadata bytes (uint8)

// ---------------------------------------------------------------------------
// Kernel 1: z = logits - log(-log(clip(u))), zero arb, init score matrix
// M[b][i][j] (stride 256) with diag & column-0 = -inf.
// ---------------------------------------------------------------------------
template <typename T>
__global__ __launch_bounds__(256) void zinit_kernel(
    const float* __restrict__ logits,
    const float* __restrict__ u,
    float* __restrict__ zout,
    float* __restrict__ arb,
    T* __restrict__ M)
{
    int idx = blockIdx.x * blockDim.x + threadIdx.x;   // < Bn*Nn*Nn
    int j = idx & (Nn - 1);
    int i = (idx >> 8) & (Nn - 1);
    const float EPS = 1.1920928955078125e-07f;         // float32 eps
    float uv = u[idx];
    uv = fminf(fmaxf(uv, EPS), 1.0f - EPS);
    float z = logits[idx] - logf(-logf(uv));
    zout[idx] = z;
    arb[idx] = 0.0f;
    M[idx] = (i == j || j == 0) ? (T)(-INFINITY) : (T)z;
}

// ---------------------------------------------------------------------------
// Kernel 2: per-batch Chu-Liu/Edmonds, 256 threads/block (4 waves), in-place
// supernode contraction with active-slot indirection + incremental argmax.
// R16 (f32) structure with: merged pointer doubling (h^4 per barrier) and
// tail-free clamped+guarded batched gathers (seed 8, into/outo 8, rescan 16).
// First-max tie semantics preserved exactly (ascending-index compares).
// ---------------------------------------------------------------------------
template <typename T>
__global__ __launch_bounds__(256) void edmonds_kernel(
    const int* __restrict__ lengths,
    const float* __restrict__ zout,
    T* __restrict__ Mg,
    unsigned char* __restrict__ metag,
    float* __restrict__ arb,
    float* __restrict__ stats)
{
    const int b = blockIdx.x;
    const int t = threadIdx.x;
    const int lane = t & 63, wv = t >> 6;
    T* M = Mg + (size_t)b * (Nn * Nn);
    unsigned char* meta = metag + (size_t)b * META_PB;
    const float* zb = zout + (size_t)b * (Nn * Nn);

    __shared__ unsigned short act[256];   // compact index -> original slot
    __shared__ unsigned short h[256];     // compact heads
    __shared__ unsigned short h2[256];    // unwind ping-pong
    __shared__ unsigned short p1[256];    // pointer doubling buffer A
    __shared__ unsigned short p2[256];    // pointer doubling buffer B
    __shared__ unsigned short inv_[256];  // old compact -> new compact
    __shared__ unsigned short cyc_c[256];
    __shared__ unsigned short non_c[256];
    __shared__ unsigned short cslot_s[256];
    __shared__ unsigned short resc[256];
    __shared__ unsigned short lev_n[256], lev_c[256];
    __shared__ int lev_off[256];
    __shared__ unsigned char in_cyc[256];
    __shared__ T hval[256];               // per-column current max value
    __shared__ T chs[256];
    __shared__ double red[256];
    __shared__ unsigned wmin[4];
    __shared__ int wcnt[4];
    __shared__ int sh_clen, sh_cnt, sh_wslot;

    const int L = lengths[b];

    act[t] = (unsigned short)t;
    // ---- initial full column argmax (first-max), tail-free 8-wide ----
    if (t < L) {
        T best = -INFINITY; int bi = 0;
        const T* col = M + t;
        for (int i = 0; i < L; i += 8) {
            T v[8];
            #pragma unroll
            for (int k = 0; k < 8; ++k) {
                int ii = i + k; if (ii > L - 1) ii = L - 1;
                v[k] = col[ii * Nn];
            }
            #pragma unroll
            for (int k = 0; k < 8; ++k)
                if (i + k < L && v[k] > best) { best = v[k]; bi = i + k; }
        }
        h[t] = (t == 0) ? (unsigned short)0 : (unsigned short)bi;
        hval[t] = best;
    }
    __syncthreads();

    int Lc = L, depth = 0, moff = 0;

    while (true) {
        // ---- phase A: clear in_cyc, seed doubling buffer ----
        in_cyc[t] = 0;
        if (t < Lc) p1[t] = h[t];
        __syncthreads();

        // ---- merged pointer doubling: h^4 per round, 1 barrier each ----
        const int rounds = 32 - __clz(Lc - 1);    // ceil(log2(Lc)), Lc>=2
        const int r4 = (rounds + 1) >> 1;         // 4^r4 >= 2^rounds >= Lc
        unsigned short* pa = p1;
        unsigned short* pb = p2;
        for (int r = 0; r < r4; ++r) {
            if (t < Lc) {
                int x = pa[t];
                x = pa[x]; x = pa[x]; x = pa[x];
                pb[t] = (unsigned short)x;
            }
            __syncthreads();
            unsigned short* tmp = pa; pa = pb; pb = tmp;
        }

        // ---- min v>=1 whose chain terminates on a non-root cycle ----
        unsigned cand = (t >= 1 && t < Lc && pa[t] != 0) ? (unsigned)t : 0xFFFFu;
        for (int m = 1; m < 64; m <<= 1)
            cand = min(cand, (unsigned)__shfl_xor((int)cand, m));
        if (lane == 0) wmin[wv] = cand;
        __syncthreads();
        const unsigned vstar = min(min(wmin[0], wmin[1]), min(wmin[2], wmin[3]));
        if (vstar == 0xFFFFu) break;              // no cycle: h[] is the solution

        // ---- enumerate the cycle (thread 0, short walk) ----
        if (t == 0) {
            int w = pa[vstar];                    // a node ON the cycle
            int cl = 0, v = w;
            do { cyc_c[cl++] = (unsigned short)v; in_cyc[v] = 1; v = h[v]; }
            while (v != w);
            sh_clen = cl;
            sh_wslot = act[w];
            sh_cnt = 0;
        }
        __syncthreads();
        const int clen = sh_clen;
        const int n = Lc - clen;
        const int wslot = sh_wslot;

        // ---- non list: order-preserving compaction via ballot prefix ----
        const bool fl = (t < Lc) && !in_cyc[t];
        unsigned long long mask = __ballot(fl);
        if (lane == 0) wcnt[wv] = __popcll(mask);
        __syncthreads();
        if (fl) {
            int base = 0;
            for (int k = 0; k < wv; ++k) base += wcnt[k];
            int pos = base + __popcll(mask & ((1ull << lane) - 1ull));
            non_c[pos] = (unsigned short)t;
            inv_[t] = (unsigned short)pos;
        }
        if (t < clen) {
            const int cc = cyc_c[t];
            chs[t] = hval[cc];                    // = M[heads[cyc]][cyc]
            cslot_s[t] = act[cc];
        }
        __syncthreads();

        // ---- into (score - chs) and outo maxes, tail-free 8-wide ----
        T vin_r = (T)0, vout_r = (T)0;
        unsigned char argin_r = 0, argout_r = 0;
        int slot_r = 0;
        if (t < n) {
            slot_r = act[non_c[t]];
            T bv = -INFINITY; int bi = 0;
            T bo = -INFINITY; int bj = 0;
            for (int c = 0; c < clen; c += 8) {
                int cs[8]; T ch[8];
                #pragma unroll
                for (int k = 0; k < 8; ++k) {
                    int cc = c + k; if (cc > clen - 1) cc = clen - 1;
                    cs[k] = cslot_s[cc]; ch[k] = chs[cc];
                }
                T vi[8], vo[8];
                #pragma unroll
                for (int k = 0; k < 8; ++k) {
                    vi[k] = M[slot_r * Nn + cs[k]] - ch[k];
                    vo[k] = M[cs[k] * Nn + slot_r];
                }
                #pragma unroll
                for (int k = 0; k < 8; ++k) {
                    if (c + k < clen) {
                        if (vi[k] > bv) { bv = vi[k]; bi = c + k; }
                        if (vo[k] > bo) { bo = vo[k]; bj = c + k; }
                    }
                }
            }
            vin_r = bv; argin_r = (unsigned char)bi;
            vout_r = bo; argout_r = (unsigned char)bj;
        }

        // ---- meta push + supernode row/col writes + capture old state ----
        unsigned char* mp = meta + moff;
        if (t < n) {
            mp[t] = (unsigned char)non_c[t];
            mp[n + t] = argin_r;
            mp[2 * n + t] = argout_r;
            M[slot_r * Nn + wslot] = vin_r;       // new supernode column
            M[wslot * Nn + slot_r] = vout_r;      // new supernode row
        }
        if (t < clen) {
            mp[3 * n + t] = (unsigned char)cyc_c[t];
            mp[3 * n + clen + t] = (unsigned char)h[cyc_c[t]];
        }
        if (t == 0) {
            M[wslot * Nn + wslot] = (T)(-INFINITY);
            lev_n[depth] = (unsigned short)n;
            lev_c[depth] = (unsigned short)clen;
            lev_off[depth] = moff;
        }
        unsigned short myact = 0, myh = 0; T myhval = (T)0; bool need = false;
        if (t < n) {
            const int oc = non_c[t];
            myact = act[oc];
            const int ho = h[oc];
            need = (in_cyc[ho] != 0);
            if (!need) { myh = inv_[ho]; myhval = hval[oc]; }
        }
        __syncthreads();

        // ---- remap to new compact space ----
        if (t < n) {
            act[t] = myact;
            if (!need) { h[t] = myh; hval[t] = myhval; }
            else { int kk = atomicAdd(&sh_cnt, 1); resc[kk] = (unsigned short)t; }
        }
        if (t == 0) {
            act[n] = (unsigned short)wslot;
            int kk = atomicAdd(&sh_cnt, 1); resc[kk] = (unsigned short)n;
        }
        __syncthreads();
        moff += 3 * n + 2 * clen;
        ++depth;
        Lc = n + 1;

        // ---- rescan invalidated columns, tail-free 16-wide ----
        const int nr = sh_cnt;
        if (t < nr) {
            const int jc = resc[t];
            const int cslot = act[jc];
            T best = -INFINITY; int bi = 0;
            for (int i = 0; i < Lc; i += 16) {
                int rows[16];
                #pragma unroll
                for (int k = 0; k < 16; ++k) {
                    int ii = i + k; if (ii > Lc - 1) ii = Lc - 1;
                    rows[k] = act[ii];
                }
                T v[16];
                #pragma unroll
                for (int k = 0; k < 16; ++k) v[k] = M[rows[k] * Nn + cslot];
                #pragma unroll
                for (int k = 0; k < 16; ++k)
                    if (i + k < Lc && v[k] > best) { best = v[k]; bi = i + k; }
            }
            h[jc] = (unsigned short)bi;
            hval[jc] = best;
        }
        if (t == 0) h[0] = 0;
        __syncthreads();
    }

    // ---- unwind ----
    unsigned short* hcur = h;
    unsigned short* hnew = h2;
    for (int lvl = depth - 1; lvl >= 0; --lvl) {
        const int n = lev_n[lvl];
        const int c = lev_c[lvl];
        const unsigned char* mp = meta + lev_off[lvl];
        const unsigned char* pnon    = mp;
        const unsigned char* pargin  = mp + n;
        const unsigned char* pargout = mp + 2 * n;
        const unsigned char* pcyc    = mp + 3 * n;
        const unsigned char* phcyc   = mp + 3 * n + c;
        if (t < n) {
            const int x = hcur[t];
            hnew[pnon[t]] = (x == n) ? (unsigned short)pcyc[pargout[t]]
                                     : (unsigned short)pnon[x];
        }
        if (t < c) hnew[pcyc[t]] = phcyc[t];
        __syncthreads();
        if (t == 0) {
            const int hc = hcur[n];
            hnew[pcyc[pargin[hc]]] = pnon[hc];
            hnew[0] = 0;
        }
        __syncthreads();
        unsigned short* tmp = hcur; hcur = hnew; hnew = tmp;
    }

    // ---- emit arb (ones) and stats ----
    double acc = 0.0;
    if (t >= 1 && t < L) {
        const int hd = hcur[t];
        arb[(size_t)b * (Nn * Nn) + hd * Nn + t] = 1.0f;
        acc = (double)zb[hd * Nn + t];
    }
    red[t] = acc;
    __syncthreads();
    for (int s = 128; s > 0; s >>= 1) {
        if (t < s) red[t] += red[t + s];
        __syncthreads();
    }
    if (t == 0) stats[b] = (float)red[0];
}

// ---------------------------------------------------------------------------
extern "C" void kernel_launch(void* const* d_in, const int* in_sizes, int n_in,
                              void* d_out, int out_size, void* d_ws, size_t ws_size,
                              hipStream_t stream)
{
    const float* logits  = (const float*)d_in[0];
    const float* u       = (const float*)d_in[1];
    const int*   lengths = (const int*)d_in[2];

    float* out   = (float*)d_out;
    float* arb   = out;                                  // Bn*Nn*Nn
    float* stats = out + (size_t)Bn * Nn * Nn;           // Bn
    float* zout  = stats + Bn;                           // Bn*Nn*Nn

    const int total = Bn * Nn * Nn;
    const int zblocks = total / 256;

    const size_t mat = (size_t)Bn * Nn * Nn;

    // f32 primary: halves the gather working set so 16 blocks/XCD fit in L2.
    float* M = (float*)d_ws;
    unsigned char* meta = (unsigned char*)(M + mat);
    zinit_kernel<float><<<zblocks, 256, 0, stream>>>(logits, u, zout, arb, M);
    edmonds_kernel<float><<<Bn, 256, 0, stream>>>(lengths, zout, M, meta, arb, stats);
}

// Round 18
// 684.591 us; speedup vs baseline: 1.1433x; 1.1433x over previous
//
#include <hip/hip_runtime.h>
#include <cmath>

static constexpr int Bn = 128;
static constexpr int Nn = 256;
static constexpr int META_PB = 131072;   // per-batch metadata bytes (uint8)

// ---------------------------------------------------------------------------
// Kernel 1: z = logits - log(-log(clip(u))), zero arb, init score matrix
// M[b][i][j] (stride 256) with diag & column-0 = -inf.
// ---------------------------------------------------------------------------
template <typename T>
__global__ __launch_bounds__(256) void zinit_kernel(
    const float* __restrict__ logits,
    const float* __restrict__ u,
    float* __restrict__ zout,
    float* __restrict__ arb,
    T* __restrict__ M)
{
    int idx = blockIdx.x * blockDim.x + threadIdx.x;   // < Bn*Nn*Nn
    int j = idx & (Nn - 1);
    int i = (idx >> 8) & (Nn - 1);
    const float EPS = 1.1920928955078125e-07f;         // float32 eps
    float uv = u[idx];
    uv = fminf(fmaxf(uv, EPS), 1.0f - EPS);
    float z = logits[idx] - logf(-logf(uv));
    zout[idx] = z;
    arb[idx] = 0.0f;
    M[idx] = (i == j || j == 0) ? (T)(-INFINITY) : (T)z;
}

// ---------------------------------------------------------------------------
// Kernel 2: per-batch Chu-Liu/Edmonds, 256 threads/block (4 waves), in-place
// supernode contraction with active-slot indirection + incremental argmax.
// R16 (f32) structure EXACTLY; one change: __launch_bounds__(256, 1) frees
// the register allocator (1 block/CU anyway) so the 8/16-wide load batches
// actually stay in flight instead of being chopped to fit 32 VGPRs.
// ---------------------------------------------------------------------------
template <typename T>
__global__ __launch_bounds__(256, 1) void edmonds_kernel(
    const int* __restrict__ lengths,
    const float* __restrict__ zout,
    T* __restrict__ Mg,
    unsigned char* __restrict__ metag,
    float* __restrict__ arb,
    float* __restrict__ stats)
{
    const int b = blockIdx.x;
    const int t = threadIdx.x;
    const int lane = t & 63, wv = t >> 6;
    T* M = Mg + (size_t)b * (Nn * Nn);
    unsigned char* meta = metag + (size_t)b * META_PB;
    const float* zb = zout + (size_t)b * (Nn * Nn);

    __shared__ unsigned short act[256];   // compact index -> original slot
    __shared__ unsigned short h[256];     // compact heads
    __shared__ unsigned short h2[256];    // unwind ping-pong
    __shared__ unsigned short p1[256];    // pointer doubling buffer A
    __shared__ unsigned short p2[256];    // pointer doubling buffer B
    __shared__ unsigned short inv_[256];  // old compact -> new compact
    __shared__ unsigned short cyc_c[256];
    __shared__ unsigned short non_c[256];
    __shared__ unsigned short cslot_s[256];
    __shared__ unsigned short resc[256];
    __shared__ unsigned short lev_n[256], lev_c[256];
    __shared__ int lev_off[256];
    __shared__ unsigned char in_cyc[256];
    __shared__ T hval[256];               // per-column current max value
    __shared__ T chs[256];
    __shared__ double red[256];
    __shared__ unsigned wmin[4];
    __shared__ int wcnt[4];
    __shared__ int sh_clen, sh_cnt, sh_wslot;

    const int L = lengths[b];

    act[t] = (unsigned short)t;
    // ---- initial full column argmax (first-max), 8-wide load batching ----
    if (t < L) {
        T best = -INFINITY; int bi = 0;
        const T* col = M + t;
        int i = 0;
        for (; i + 8 <= L; i += 8) {
            T v[8];
            #pragma unroll
            for (int k = 0; k < 8; ++k) v[k] = col[(i + k) * Nn];
            #pragma unroll
            for (int k = 0; k < 8; ++k)
                if (v[k] > best) { best = v[k]; bi = i + k; }
        }
        for (; i < L; ++i) {
            T v = col[i * Nn];
            if (v > best) { best = v; bi = i; }
        }
        h[t] = (t == 0) ? (unsigned short)0 : (unsigned short)bi;
        hval[t] = best;
    }
    __syncthreads();

    int Lc = L, depth = 0, moff = 0;

    while (true) {
        // ---- phase A: clear in_cyc, seed doubling buffer ----
        in_cyc[t] = 0;
        if (t < Lc) p1[t] = h[t];
        __syncthreads();

        // ---- pointer doubling, ping-pong, 1 barrier per round ----
        const int rounds = 32 - __clz(Lc - 1);    // ceil(log2(Lc)), Lc>=2
        unsigned short* pa = p1;
        unsigned short* pb = p2;
        for (int r = 0; r < rounds; ++r) {
            if (t < Lc) pb[t] = pa[pa[t]];
            __syncthreads();
            unsigned short* tmp = pa; pa = pb; pb = tmp;
        }

        // ---- min v>=1 whose chain terminates on a non-root cycle ----
        unsigned cand = (t >= 1 && t < Lc && pa[t] != 0) ? (unsigned)t : 0xFFFFu;
        for (int m = 1; m < 64; m <<= 1)
            cand = min(cand, (unsigned)__shfl_xor((int)cand, m));
        if (lane == 0) wmin[wv] = cand;
        __syncthreads();
        const unsigned vstar = min(min(wmin[0], wmin[1]), min(wmin[2], wmin[3]));
        if (vstar == 0xFFFFu) break;              // no cycle: h[] is the solution

        // ---- enumerate the cycle (thread 0, short walk) ----
        if (t == 0) {
            int w = pa[vstar];                    // a node ON the cycle
            int cl = 0, v = w;
            do { cyc_c[cl++] = (unsigned short)v; in_cyc[v] = 1; v = h[v]; }
            while (v != w);
            sh_clen = cl;
            sh_wslot = act[w];
            sh_cnt = 0;
        }
        __syncthreads();
        const int clen = sh_clen;
        const int n = Lc - clen;
        const int wslot = sh_wslot;

        // ---- non list: order-preserving compaction via ballot prefix ----
        const bool fl = (t < Lc) && !in_cyc[t];
        unsigned long long mask = __ballot(fl);
        if (lane == 0) wcnt[wv] = __popcll(mask);
        __syncthreads();
        if (fl) {
            int base = 0;
            for (int k = 0; k < wv; ++k) base += wcnt[k];
            int pos = base + __popcll(mask & ((1ull << lane) - 1ull));
            non_c[pos] = (unsigned short)t;
            inv_[t] = (unsigned short)pos;
        }
        if (t < clen) {
            const int cc = cyc_c[t];
            chs[t] = hval[cc];                    // = M[heads[cyc]][cyc]
            cslot_s[t] = act[cc];
        }
        __syncthreads();

        // ---- into (score - chs) and outo maxes, 4-wide load batching ----
        T vin_r = (T)0, vout_r = (T)0;
        unsigned char argin_r = 0, argout_r = 0;
        int slot_r = 0;
        if (t < n) {
            slot_r = act[non_c[t]];
            T bv = -INFINITY; int bi = 0;
            T bo = -INFINITY; int bj = 0;
            int c = 0;
            for (; c + 4 <= clen; c += 4) {
                int cs[4]; T ch[4];
                #pragma unroll
                for (int k = 0; k < 4; ++k) { cs[k] = cslot_s[c + k]; ch[k] = chs[c + k]; }
                T vi[4], vo[4];
                #pragma unroll
                for (int k = 0; k < 4; ++k) {
                    vi[k] = M[slot_r * Nn + cs[k]] - ch[k];
                    vo[k] = M[cs[k] * Nn + slot_r];
                }
                #pragma unroll
                for (int k = 0; k < 4; ++k) {
                    if (vi[k] > bv) { bv = vi[k]; bi = c + k; }
                    if (vo[k] > bo) { bo = vo[k]; bj = c + k; }
                }
            }
            for (; c < clen; ++c) {
                const int cs = cslot_s[c];
                T vi = M[slot_r * Nn + cs] - chs[c];
                T vo = M[cs * Nn + slot_r];
                if (vi > bv) { bv = vi; bi = c; }
                if (vo > bo) { bo = vo; bj = c; }
            }
            vin_r = bv; argin_r = (unsigned char)bi;
            vout_r = bo; argout_r = (unsigned char)bj;
        }

        // ---- meta push + supernode row/col writes + capture old state ----
        unsigned char* mp = meta + moff;
        if (t < n) {
            mp[t] = (unsigned char)non_c[t];
            mp[n + t] = argin_r;
            mp[2 * n + t] = argout_r;
            M[slot_r * Nn + wslot] = vin_r;       // new supernode column
            M[wslot * Nn + slot_r] = vout_r;      // new supernode row
        }
        if (t < clen) {
            mp[3 * n + t] = (unsigned char)cyc_c[t];
            mp[3 * n + clen + t] = (unsigned char)h[cyc_c[t]];
        }
        if (t == 0) {
            M[wslot * Nn + wslot] = (T)(-INFINITY);
            lev_n[depth] = (unsigned short)n;
            lev_c[depth] = (unsigned short)clen;
            lev_off[depth] = moff;
        }
        unsigned short myact = 0, myh = 0; T myhval = (T)0; bool need = false;
        if (t < n) {
            const int oc = non_c[t];
            myact = act[oc];
            const int ho = h[oc];
            need = (in_cyc[ho] != 0);
            if (!need) { myh = inv_[ho]; myhval = hval[oc]; }
        }
        __syncthreads();

        // ---- remap to new compact space ----
        if (t < n) {
            act[t] = myact;
            if (!need) { h[t] = myh; hval[t] = myhval; }
            else { int kk = atomicAdd(&sh_cnt, 1); resc[kk] = (unsigned short)t; }
        }
        if (t == 0) {
            act[n] = (unsigned short)wslot;
            int kk = atomicAdd(&sh_cnt, 1); resc[kk] = (unsigned short)n;
        }
        __syncthreads();
        moff += 3 * n + 2 * clen;
        ++depth;
        Lc = n + 1;

        // ---- rescan invalidated columns, 16-wide load batching ----
        const int nr = sh_cnt;
        if (t < nr) {
            const int jc = resc[t];
            const int cslot = act[jc];
            T best = -INFINITY; int bi = 0;
            int i = 0;
            for (; i + 16 <= Lc; i += 16) {
                int rows[16];
                #pragma unroll
                for (int k = 0; k < 16; ++k) rows[k] = act[i + k];
                T v[16];
                #pragma unroll
                for (int k = 0; k < 16; ++k) v[k] = M[rows[k] * Nn + cslot];
                #pragma unroll
                for (int k = 0; k < 16; ++k)
                    if (v[k] > best) { best = v[k]; bi = i + k; }
            }
            for (; i < Lc; ++i) {
                T v = M[(int)act[i] * Nn + cslot];
                if (v > best) { best = v; bi = i; }
            }
            h[jc] = (unsigned short)bi;
            hval[jc] = best;
        }
        if (t == 0) h[0] = 0;
        __syncthreads();
    }

    // ---- unwind ----
    unsigned short* hcur = h;
    unsigned short* hnew = h2;
    for (int lvl = depth - 1; lvl >= 0; --lvl) {
        const int n = lev_n[lvl];
        const int c = lev_c[lvl];
        const unsigned char* mp = meta + lev_off[lvl];
        const unsigned char* pnon    = mp;
        const unsigned char* pargin  = mp + n;
        const unsigned char* pargout = mp + 2 * n;
        const unsigned char* pcyc    = mp + 3 * n;
        const unsigned char* phcyc   = mp + 3 * n + c;
        if (t < n) {
            const int x = hcur[t];
            hnew[pnon[t]] = (x == n) ? (unsigned short)pcyc[pargout[t]]
                                     : (unsigned short)pnon[x];
        }
        if (t < c) hnew[pcyc[t]] = phcyc[t];
        __syncthreads();
        if (t == 0) {
            const int hc = hcur[n];
            hnew[pcyc[pargin[hc]]] = pnon[hc];
            hnew[0] = 0;
        }
        __syncthreads();
        unsigned short* tmp = hcur; hcur = hnew; hnew = tmp;
    }

    // ---- emit arb (ones) and stats ----
    double acc = 0.0;
    if (t >= 1 && t < L) {
        const int hd = hcur[t];
        arb[(size_t)b * (Nn * Nn) + hd * Nn + t] = 1.0f;
        acc = (double)zb[hd * Nn + t];
    }
    red[t] = acc;
    __syncthreads();
    for (int s = 128; s > 0; s >>= 1) {
        if (t < s) red[t] += red[t + s];
        __syncthreads();
    }
    if (t == 0) stats[b] = (float)red[0];
}

// ---------------------------------------------------------------------------
extern "C" void kernel_launch(void* const* d_in, const int* in_sizes, int n_in,
                              void* d_out, int out_size, void* d_ws, size_t ws_size,
                              hipStream_t stream)
{
    const float* logits  = (const float*)d_in[0];
    const float* u       = (const float*)d_in[1];
    const int*   lengths = (const int*)d_in[2];

    float* out   = (float*)d_out;
    float* arb   = out;                                  // Bn*Nn*Nn
    float* stats = out + (size_t)Bn * Nn * Nn;           // Bn
    float* zout  = stats + Bn;                           // Bn*Nn*Nn

    const int total = Bn * Nn * Nn;
    const int zblocks = total / 256;

    const size_t mat = (size_t)Bn * Nn * Nn;

    // f32 primary: halves the gather working set so 16 blocks/XCD fit in L2.
    float* M = (float*)d_ws;
    unsigned char* meta = (unsigned char*)(M + mat);
    zinit_kernel<float><<<zblocks, 256, 0, stream>>>(logits, u, zout, arb, M);
    edmonds_kernel<float><<<Bn, 256, 0, stream>>>(lengths, zout, M, meta, arb, stats);
}